// Round 3
// baseline (204.035 us; speedup 1.0000x reference)
//
#include <hip/hip_runtime.h>

// ---------- types ----------
typedef _Float16 f16x8 __attribute__((ext_vector_type(8)));
typedef _Float16 f16x4 __attribute__((ext_vector_type(4)));
typedef _Float16 f16x2 __attribute__((ext_vector_type(2)));
typedef float    f32x4 __attribute__((ext_vector_type(4)));
typedef float    f32x16 __attribute__((ext_vector_type(16)));
typedef unsigned int u32x4 __attribute__((ext_vector_type(4)));
typedef unsigned short ushort_t;
typedef unsigned int uint_t;

#define LOG2E 1.44269504088896340736f

__device__ __forceinline__ ushort_t f2h(float x) {
  _Float16 h = (_Float16)x;
  return __builtin_bit_cast(ushort_t, h);
}

__device__ __forceinline__ uint_t packpair(float a, float b) {
  return __builtin_bit_cast(uint_t, __builtin_amdgcn_cvt_pkrtz(a, b));
}

__device__ __forceinline__ f16x8 mk8(uint_t a, uint_t b, uint_t c, uint_t d) {
  u32x4 t; t[0] = a; t[1] = b; t[2] = c; t[3] = d;
  return __builtin_bit_cast(f16x8, t);
}

// async global->LDS, 16B per lane. LDS dest is wave-uniform base + lane*16.
__device__ __forceinline__ void gload_lds16(const void* g, void* lds) {
  __builtin_amdgcn_global_load_lds(
      (const __attribute__((address_space(1))) void*)(uintptr_t)g,
      (__attribute__((address_space(3))) void*)(unsigned)(uintptr_t)lds,
      16, 0, 0);
}

// ---------- LocalRmsNorm: pass A (horizontal 7-tap box of x^2) -> f16 tmp ----------
__global__ __launch_bounds__(256)
void lrn_a(const float* __restrict__ x, ushort_t* __restrict__ tmp) {
  int tid = blockIdx.x * 256 + threadIdx.x;     // 8*1024*192 threads
  int dv  = tid % 192;
  int rem = tid / 192;
  int pos = rem & 1023;
  int b   = rem >> 10;
  int r = pos >> 5, c = pos & 31;
  const float4* base = (const float4*)x + ((size_t)b * 1024 + (size_t)r * 32) * 192 + dv;
  float ax = 0.f, ay = 0.f, az = 0.f, aw = 0.f;
#pragma unroll
  for (int dc = -3; dc <= 3; ++dc) {
    int cc = c + dc;
    if (cc >= 0 && cc < 32) {
      float4 v = base[cc * 192];
      ax += v.x * v.x; ay += v.y * v.y; az += v.z * v.z; aw += v.w * v.w;
    }
  }
  f16x4 o;
  o[0] = (_Float16)ax; o[1] = (_Float16)ay; o[2] = (_Float16)az; o[3] = (_Float16)aw;
  *(f16x4*)(tmp + (size_t)tid * 4) = o;
}

// ---------- LocalRmsNorm: pass B (vertical 7-tap) -> xn (f16) ----------
__global__ __launch_bounds__(256)
void lrn_b(const float* __restrict__ x, const ushort_t* __restrict__ tmp,
           const float* __restrict__ wn, ushort_t* __restrict__ xn) {
  int tid = blockIdx.x * 256 + threadIdx.x;
  int dv  = tid % 192;
  int rem = tid / 192;
  int pos = rem & 1023;
  int b   = rem >> 10;
  int r = pos >> 5, c = pos & 31;
  const ushort_t* tb = tmp + (((size_t)b * 1024 + c) * 192 + dv) * 4;
  float ax = 0.f, ay = 0.f, az = 0.f, aw = 0.f;
#pragma unroll
  for (int dr = -3; dr <= 3; ++dr) {
    int rr = r + dr;
    if (rr >= 0 && rr < 32) {
      f16x4 v = *(const f16x4*)(tb + (size_t)rr * 24576);
      ax += (float)v[0]; ay += (float)v[1]; az += (float)v[2]; aw += (float)v[3];
    }
  }
  float4 xv = ((const float4*)x)[tid];
  float4 wv = ((const float4*)wn)[dv];
  const float inv49 = 1.0f / 49.0f;
  float i0 = 1.0f / sqrtf(1e-7f + ax * inv49);
  float i1 = 1.0f / sqrtf(1e-7f + ay * inv49);
  float i2 = 1.0f / sqrtf(1e-7f + az * inv49);
  float i3 = 1.0f / sqrtf(1e-7f + aw * inv49);
  f16x4 o;
  o[0] = (_Float16)(xv.x * i0 * wv.x);
  o[1] = (_Float16)(xv.y * i1 * wv.y);
  o[2] = (_Float16)(xv.z * i2 * wv.z);
  o[3] = (_Float16)(xv.w * i3 * wv.w);
  *(f16x4*)(xn + (size_t)tid * 4) = o;
}

// ---------- weight conversion f32 -> f16 ----------
__global__ __launch_bounds__(256)
void convw(const float* __restrict__ wq, const float* __restrict__ wk,
           const float* __restrict__ wv, const float* __restrict__ wo,
           ushort_t* __restrict__ bqkv, ushort_t* __restrict__ bwo) {
  int tid = blockIdx.x * 256 + threadIdx.x;   // 589824/4 threads
  float4 a = ((const float4*)wq)[tid];
  float4 b = ((const float4*)wk)[tid];
  float4 c = ((const float4*)wv)[tid];
  float4 d = ((const float4*)wo)[tid];
  f16x4 pa, pb, pc, pd;
  pa[0]=(_Float16)a.x; pa[1]=(_Float16)a.y; pa[2]=(_Float16)a.z; pa[3]=(_Float16)a.w;
  pb[0]=(_Float16)b.x; pb[1]=(_Float16)b.y; pb[2]=(_Float16)b.z; pb[3]=(_Float16)b.w;
  pc[0]=(_Float16)c.x; pc[1]=(_Float16)c.y; pc[2]=(_Float16)c.z; pc[3]=(_Float16)c.w;
  pd[0]=(_Float16)d.x; pd[1]=(_Float16)d.y; pd[2]=(_Float16)d.z; pd[3]=(_Float16)d.w;
  ((f16x4*)bqkv)[tid]             = pa;
  ((f16x4*)(bqkv + 589824))[tid]  = pb;
  ((f16x4*)(bqkv + 1179648))[tid] = pc;
  ((f16x4*)bwo)[tid]              = pd;
}

// ---------- GEMM: out[m][n] = sum_k A[m][k]*B[n][k] (+bias) ----------
// MODE 0: N=2304 -> scatter Q (scaled 0.125*log2e), K, V^T kv-permuted (f16)
// MODE 1: N=768  -> d_out fp32 row-major
template <int MODE>
__global__ __launch_bounds__(256)
void gemm_f16(const ushort_t* __restrict__ A, const ushort_t* __restrict__ B,
              const float* __restrict__ b0, const float* __restrict__ b1,
              const float* __restrict__ b2,
              ushort_t* __restrict__ q, ushort_t* __restrict__ k,
              ushort_t* __restrict__ v, float* __restrict__ outf, int nbn) {
  __shared__ __align__(16) ushort_t As[128 * 32];
  __shared__ __align__(16) ushort_t Bs[128 * 32];

  const int bid = blockIdx.x;
  const int bm = bid / nbn, bn = bid % nbn;
  const int tid = threadIdx.x;
  const int w = tid >> 6, l = tid & 63;
  const int wr = w >> 1, wc = w & 1;
  const int lr = l & 15, lg = l >> 4;

  f32x4 acc[4][4] = {};

  const ushort_t* Ab = A + (size_t)bm * 128 * 768;
  const ushort_t* Bb = B + (size_t)bn * 128 * 768;
  const int srow = w * 32 + (l >> 2);
  const int scol = (l & 3) * 8;

  for (int kt = 0; kt < 24; ++kt) {
    const int k0 = kt * 32;
    gload_lds16(Ab + (size_t)srow * 768 + k0 + scol,        As + (w * 32) * 32);
    gload_lds16(Ab + (size_t)(srow + 16) * 768 + k0 + scol, As + (w * 32 + 16) * 32);
    gload_lds16(Bb + (size_t)srow * 768 + k0 + scol,        Bs + (w * 32) * 32);
    gload_lds16(Bb + (size_t)(srow + 16) * 768 + k0 + scol, Bs + (w * 32 + 16) * 32);
    __syncthreads();
    f16x8 af[4], bf[4];
#pragma unroll
    for (int r = 0; r < 4; ++r)
      af[r] = *(const f16x8*)(As + (wr * 64 + r * 16 + lr) * 32 + lg * 8);
#pragma unroll
    for (int c = 0; c < 4; ++c)
      bf[c] = *(const f16x8*)(Bs + (wc * 64 + c * 16 + lr) * 32 + lg * 8);
#pragma unroll
    for (int r = 0; r < 4; ++r)
#pragma unroll
      for (int c = 0; c < 4; ++c)
        acc[r][c] = __builtin_amdgcn_mfma_f32_16x16x32_f16(af[r], bf[c], acc[r][c], 0, 0, 0);
    __syncthreads();
  }

  // epilogue. C/D layout: col = lane&15, row = (lane>>4)*4 + reg  [m89/m91]
#pragma unroll
  for (int r = 0; r < 4; ++r) {
#pragma unroll
    for (int c = 0; c < 4; ++c) {
      const int n = bn * 128 + wc * 64 + c * 16 + lr;
      const int mbase = bm * 128 + wr * 64 + r * 16 + lg * 4;
      if (MODE == 0) {
        const int region = n / 768;          // uniform per block (768%128==0)
        const int nn = n - region * 768;
        const int hh = nn >> 6, hd = nn & 63;
        const float bb = (region == 0 ? b0 : region == 1 ? b1 : b2)[nn];
        if (region == 2) {
          // V^T with kv-permuted columns: token s -> column tile*64 + sigma^{-1}(s&63),
          // so PV's B-frag k-slot ordering matches P's in-register layout.
          const int bi = mbase >> 10, s0 = mbase & 1023;
          const int tile = s0 >> 6, q6 = s0 & 63;
          const int aa = q6 >> 5, r5 = q6 & 31;
          const int t1 = r5 >> 3, h2 = (r5 >> 2) & 1;
          const int g = t1 >> 1, j = (2 * t1) & 3;
          const int s0p = (tile << 6) + (((aa << 1) + g) << 4) + (h2 << 3) + 2 * j;
          f16x4 pv;
#pragma unroll
          for (int gi = 0; gi < 4; ++gi) pv[gi] = (_Float16)(acc[r][c][gi] + bb);
          *(f16x4*)(v + (((size_t)(bi * 12 + hh)) * 64 + hd) * 1024 + s0p) = pv;
        } else {
#pragma unroll
          for (int gi = 0; gi < 4; ++gi) {
            const int m = mbase + gi;
            const int bi = m >> 10, s = m & 1023;
            const float val = acc[r][c][gi] + bb;
            if (region == 0)
              q[(((size_t)(bi * 12 + hh)) * 1024 + s) * 64 + hd] = f2h(val * (0.125f * LOG2E));
            else
              k[(((size_t)(bi * 12 + hh)) * 1024 + s) * 64 + hd] = f2h(val);
          }
        }
      } else {
        const float bb = b0[n];
#pragma unroll
        for (int gi = 0; gi < 4; ++gi) {
          const int m = mbase + gi;
          outf[(size_t)m * 768 + n] = acc[r][c][gi] + bb;
        }
      }
    }
  }
}

// ---------- fused flash attention v3: barrier-free, direct-global K/V ----------
// qb: [96][1024][64] f16 (scaled 0.125*log2e), kb: [96][1024][64] f16,
// vt: [96][64][1024] f16 with kv-permuted columns per 64-tile.
// 4 waves/block, 32 q-rows/wave, K/V read straight from L2 (256KB/head,
// XCD-pinned). No LDS, no __syncthreads in the main loop -> waves independent.
__global__ __launch_bounds__(256, 3)
void attn_fused3(const ushort_t* __restrict__ qb, const ushort_t* __restrict__ kb,
                 const ushort_t* __restrict__ vt, ushort_t* __restrict__ ao) {
  __shared__ __align__(16) ushort_t smem[8192];   // 16KB, epilogue transpose only
  const int tid = threadIdx.x;
  const int w = tid >> 6, l = tid & 63;
  const int lq = l & 31, hi = l >> 5;

  // XCD-contiguous remap: 96 consecutive cids per XCD = 12 heads x 8 q-tiles
  const int bid = blockIdx.x;
  const int cid = (bid & 7) * 96 + (bid >> 3);
  const int bh = cid >> 3, qt = cid & 7;
  const int b = bh / 12, h = bh % 12;

  const ushort_t* qp = qb + ((size_t)bh * 1024 + qt * 128 + w * 32) * 64;
  const ushort_t* kp = kb + (size_t)bh * 65536;
  const ushort_t* vp = vt + (size_t)bh * 65536;

  // Q B-frags: col q = lq, k = kc*16 + hi*8 + i
  f16x8 qf[4];
#pragma unroll
  for (int kc = 0; kc < 4; ++kc)
    qf[kc] = *(const f16x8*)(qp + lq * 64 + kc * 16 + hi * 8);

  f32x16 oacc0 = {}, oacc1 = {};
  float mrun = -1e30f;
  float lr0 = 0.f, lr1 = 0.f, lr2 = 0.f, lr3 = 0.f;
  const f16x2 one2 = {(_Float16)1.f, (_Float16)1.f};

  const ushort_t* krow = kp + (size_t)lq * 64 + hi * 8;          // A-frag row kv0+lq
  const ushort_t* vrow0 = vp + (size_t)lq * 1024 + hi * 8;       // A-frag row d=lq
  const ushort_t* vrow1 = vp + (size_t)(lq + 32) * 1024 + hi * 8;

  for (int t = 0; t < 16; ++t) {
    const int kv0 = t * 64;
    const ushort_t* k0 = krow + (size_t)kv0 * 64;
    f16x8 ka0[4], ka1[4];
#pragma unroll
    for (int kc = 0; kc < 4; ++kc) {
      ka0[kc] = *(const f16x8*)(k0 + kc * 16);
      ka1[kc] = *(const f16x8*)(k0 + 2048 + kc * 16);   // rows kv0+32+lq
    }
    f32x16 s0 = {}, s1 = {};
    __builtin_amdgcn_s_setprio(1);
#pragma unroll
    for (int kc = 0; kc < 4; ++kc) {
      s0 = __builtin_amdgcn_mfma_f32_32x32x16_f16(ka0[kc], qf[kc], s0, 0, 0, 0);
      s1 = __builtin_amdgcn_mfma_f32_32x32x16_f16(ka1[kc], qf[kc], s1, 0, 0, 0);
    }
    __builtin_amdgcn_s_setprio(0);

    // V loads issued early; latency hides under the softmax VALU below
    f16x8 va0[4], va1[4];
#pragma unroll
    for (int c = 0; c < 4; ++c) {
      va0[c] = *(const f16x8*)(vrow0 + kv0 + c * 16);
      va1[c] = *(const f16x8*)(vrow1 + kv0 + c * 16);
    }

    // ---- online softmax, lane-local, defer-max (T13) ----
    float mt = -1e30f;
#pragma unroll
    for (int r = 0; r < 16; ++r) mt = fmaxf(mt, fmaxf(s0[r], s1[r]));
    mt = fmaxf(mt, __shfl_xor(mt, 32, 64));   // sync q-column pair (hi 0/1)
    if (__any(mt > mrun + 8.f)) {
      const float mnew = fmaxf(mrun, mt);
      const float corr = __builtin_exp2f(mrun - mnew);
      lr0 *= corr; lr1 *= corr; lr2 *= corr; lr3 *= corr;
#pragma unroll
      for (int r = 0; r < 16; ++r) { oacc0[r] *= corr; oacc1[r] *= corr; }
      mrun = mnew;
    }

    uint_t pk0[8], pk1[8];
#pragma unroll
    for (int tt = 0; tt < 8; ++tt) {
      pk0[tt] = packpair(__builtin_exp2f(s0[2 * tt] - mrun),
                         __builtin_exp2f(s0[2 * tt + 1] - mrun));
      pk1[tt] = packpair(__builtin_exp2f(s1[2 * tt] - mrun),
                         __builtin_exp2f(s1[2 * tt + 1] - mrun));
#if !__has_builtin(__builtin_amdgcn_fdot2)
      lr0 += __builtin_exp2f(s0[2 * tt] - mrun) + __builtin_exp2f(s0[2 * tt + 1] - mrun);
      lr2 += __builtin_exp2f(s1[2 * tt] - mrun) + __builtin_exp2f(s1[2 * tt + 1] - mrun);
#endif
    }
#if __has_builtin(__builtin_amdgcn_fdot2)
#pragma unroll
    for (int tt = 0; tt < 4; ++tt) {
      lr0 = __builtin_amdgcn_fdot2(__builtin_bit_cast(f16x2, pk0[tt]),     one2, lr0, false);
      lr1 = __builtin_amdgcn_fdot2(__builtin_bit_cast(f16x2, pk0[tt + 4]), one2, lr1, false);
      lr2 = __builtin_amdgcn_fdot2(__builtin_bit_cast(f16x2, pk1[tt]),     one2, lr2, false);
      lr3 = __builtin_amdgcn_fdot2(__builtin_bit_cast(f16x2, pk1[tt + 4]), one2, lr3, false);
    }
#endif

    const f16x8 pb0 = mk8(pk0[0], pk0[1], pk0[2], pk0[3]);
    const f16x8 pb1 = mk8(pk0[4], pk0[5], pk0[6], pk0[7]);
    const f16x8 pb2 = mk8(pk1[0], pk1[1], pk1[2], pk1[3]);
    const f16x8 pb3 = mk8(pk1[4], pk1[5], pk1[6], pk1[7]);

    __builtin_amdgcn_s_setprio(1);
    oacc0 = __builtin_amdgcn_mfma_f32_32x32x16_f16(va0[0], pb0, oacc0, 0, 0, 0);
    oacc1 = __builtin_amdgcn_mfma_f32_32x32x16_f16(va1[0], pb0, oacc1, 0, 0, 0);
    oacc0 = __builtin_amdgcn_mfma_f32_32x32x16_f16(va0[1], pb1, oacc0, 0, 0, 0);
    oacc1 = __builtin_amdgcn_mfma_f32_32x32x16_f16(va1[1], pb1, oacc1, 0, 0, 0);
    oacc0 = __builtin_amdgcn_mfma_f32_32x32x16_f16(va0[2], pb2, oacc0, 0, 0, 0);
    oacc1 = __builtin_amdgcn_mfma_f32_32x32x16_f16(va1[2], pb2, oacc1, 0, 0, 0);
    oacc0 = __builtin_amdgcn_mfma_f32_32x32x16_f16(va0[3], pb3, oacc0, 0, 0, 0);
    oacc1 = __builtin_amdgcn_mfma_f32_32x32x16_f16(va1[3], pb3, oacc1, 0, 0, 0);
    __builtin_amdgcn_s_setprio(0);
  }

  // ---- finalize l across halves (single cross-lane op for the whole kernel) ----
  float lrun = (lr0 + lr1) + (lr2 + lr3);
  lrun += __shfl_xor(lrun, 32, 64);
  const float invl = 1.0f / lrun;

  // ---- epilogue: O^T -> swizzled LDS -> coalesced global f16 rows ----
  uint_t* ot = (uint_t*)smem + w * 1024 + lq * 32;   // wave-private 4KB tile
#pragma unroll
  for (int tt = 0; tt < 8; ++tt) {
    const int base = (tt & 1) + ((tt >> 1) << 2) + 2 * hi;
    ot[base ^ lq]        = packpair(oacc0[2 * tt] * invl, oacc0[2 * tt + 1] * invl);
    ot[(base + 16) ^ lq] = packpair(oacc1[2 * tt] * invl, oacc1[2 * tt + 1] * invl);
  }
  __syncthreads();
  const int row = tid >> 1, halfc = tid & 1;        // row 0..127
  const int w2 = row >> 5, qq = row & 31;
  const uint_t* srcp = (const uint_t*)smem + w2 * 1024 + qq * 32;
  ushort_t* dst = ao + (size_t)(b * 1024 + qt * 128 + row) * 768 + h * 64 + halfc * 32;
#pragma unroll
  for (int jj = 0; jj < 4; ++jj) {
    u32x4 tv;
#pragma unroll
    for (int i2 = 0; i2 < 4; ++i2)
      tv[i2] = srcp[(halfc * 16 + jj * 4 + i2) ^ qq];
    *(u32x4*)(dst + jj * 8) = tv;
  }
}

// ---------- launch ----------
extern "C" void kernel_launch(void* const* d_in, const int* in_sizes, int n_in,
                              void* d_out, int out_size, void* d_ws, size_t ws_size,
                              hipStream_t stream) {
  const float* x  = (const float*)d_in[0];
  const float* nw = (const float*)d_in[1];
  const float* wq = (const float*)d_in[2];
  const float* bq = (const float*)d_in[3];
  const float* wk = (const float*)d_in[4];
  const float* bk = (const float*)d_in[5];
  const float* wv = (const float*)d_in[6];
  const float* bv = (const float*)d_in[7];
  const float* wo = (const float*)d_in[8];
  const float* bo = (const float*)d_in[9];
  float* out = (float*)d_out;

  char* ws = (char*)d_ws;
  // tmp (12.58MB f16) is consumed by lrn_b, then its region is reused for qbuf.
  ushort_t* tmp   = (ushort_t*)ws;
  ushort_t* qbuf  = (ushort_t*)(ws);
  ushort_t* kbuf  = (ushort_t*)(ws + 12582912);
  ushort_t* xn    = (ushort_t*)(ws + 25165824);   // 12,582,912
  ushort_t* bwqkv = (ushort_t*)(ws + 37748736);   //  3,538,944
  ushort_t* bwo   = (ushort_t*)(ws + 41287680);   //  1,179,648
  ushort_t* vtb   = (ushort_t*)(ws + 42467328);   // 12,582,912
  ushort_t* aout  = (ushort_t*)(ws + 55050240);   // 12,582,912  (total 67,633,152)

  lrn_a<<<6144, 256, 0, stream>>>(x, tmp);
  lrn_b<<<6144, 256, 0, stream>>>(x, tmp, nw, xn);
  convw<<<576, 256, 0, stream>>>(wq, wk, wv, wo, bwqkv, bwo);
  gemm_f16<0><<<64 * 18, 256, 0, stream>>>(xn, bwqkv, bq, bk, bv,
                                           qbuf, kbuf, vtb, nullptr, 18);
  attn_fused3<<<768, 256, 0, stream>>>(qbuf, kbuf, vtb, aout);
  gemm_f16<1><<<64 * 6, 256, 0, stream>>>(aout, bwo, bo, nullptr, nullptr, nullptr,
                                          nullptr, nullptr, out, 6);
}

// Round 4
// 165.877 us; speedup vs baseline: 1.2300x; 1.2300x over previous
//
#include <hip/hip_runtime.h>

// ---------- types ----------
typedef _Float16 f16x8 __attribute__((ext_vector_type(8)));
typedef _Float16 f16x4 __attribute__((ext_vector_type(4)));
typedef _Float16 f16x2 __attribute__((ext_vector_type(2)));
typedef float    f32x4 __attribute__((ext_vector_type(4)));
typedef float    f32x16 __attribute__((ext_vector_type(16)));
typedef unsigned int u32x4 __attribute__((ext_vector_type(4)));
typedef unsigned short ushort_t;
typedef unsigned int uint_t;

#define LOG2E 1.44269504088896340736f

__device__ __forceinline__ ushort_t f2h(float x) {
  _Float16 h = (_Float16)x;
  return __builtin_bit_cast(ushort_t, h);
}

__device__ __forceinline__ uint_t packpair(float a, float b) {
  return __builtin_bit_cast(uint_t, __builtin_amdgcn_cvt_pkrtz(a, b));
}

__device__ __forceinline__ f16x8 mk8(uint_t a, uint_t b, uint_t c, uint_t d) {
  u32x4 t; t[0] = a; t[1] = b; t[2] = c; t[3] = d;
  return __builtin_bit_cast(f16x8, t);
}

// async global->LDS, 16B per lane. LDS dest is wave-uniform base + lane*16.
__device__ __forceinline__ void gload_lds16(const void* g, void* lds) {
  __builtin_amdgcn_global_load_lds(
      (const __attribute__((address_space(1))) void*)(uintptr_t)g,
      (__attribute__((address_space(3))) void*)(unsigned)(uintptr_t)lds,
      16, 0, 0);
}

// ---------- LocalRmsNorm: pass A (horizontal 7-tap box of x^2) -> f16 tmp ----------
__global__ __launch_bounds__(256)
void lrn_a(const float* __restrict__ x, ushort_t* __restrict__ tmp) {
  int tid = blockIdx.x * 256 + threadIdx.x;     // 8*1024*192 threads
  int dv  = tid % 192;
  int rem = tid / 192;
  int pos = rem & 1023;
  int b   = rem >> 10;
  int r = pos >> 5, c = pos & 31;
  const float4* base = (const float4*)x + ((size_t)b * 1024 + (size_t)r * 32) * 192 + dv;
  float ax = 0.f, ay = 0.f, az = 0.f, aw = 0.f;
#pragma unroll
  for (int dc = -3; dc <= 3; ++dc) {
    int cc = c + dc;
    if (cc >= 0 && cc < 32) {
      float4 v = base[cc * 192];
      ax += v.x * v.x; ay += v.y * v.y; az += v.z * v.z; aw += v.w * v.w;
    }
  }
  f16x4 o;
  o[0] = (_Float16)ax; o[1] = (_Float16)ay; o[2] = (_Float16)az; o[3] = (_Float16)aw;
  *(f16x4*)(tmp + (size_t)tid * 4) = o;
}

// ---------- LocalRmsNorm: pass B (vertical 7-tap) -> xn (f16) ----------
__global__ __launch_bounds__(256)
void lrn_b(const float* __restrict__ x, const ushort_t* __restrict__ tmp,
           const float* __restrict__ wn, ushort_t* __restrict__ xn) {
  int tid = blockIdx.x * 256 + threadIdx.x;
  int dv  = tid % 192;
  int rem = tid / 192;
  int pos = rem & 1023;
  int b   = rem >> 10;
  int r = pos >> 5, c = pos & 31;
  const ushort_t* tb = tmp + (((size_t)b * 1024 + c) * 192 + dv) * 4;
  float ax = 0.f, ay = 0.f, az = 0.f, aw = 0.f;
#pragma unroll
  for (int dr = -3; dr <= 3; ++dr) {
    int rr = r + dr;
    if (rr >= 0 && rr < 32) {
      f16x4 v = *(const f16x4*)(tb + (size_t)rr * 24576);
      ax += (float)v[0]; ay += (float)v[1]; az += (float)v[2]; aw += (float)v[3];
    }
  }
  float4 xv = ((const float4*)x)[tid];
  float4 wv = ((const float4*)wn)[dv];
  const float inv49 = 1.0f / 49.0f;
  float i0 = 1.0f / sqrtf(1e-7f + ax * inv49);
  float i1 = 1.0f / sqrtf(1e-7f + ay * inv49);
  float i2 = 1.0f / sqrtf(1e-7f + az * inv49);
  float i3 = 1.0f / sqrtf(1e-7f + aw * inv49);
  f16x4 o;
  o[0] = (_Float16)(xv.x * i0 * wv.x);
  o[1] = (_Float16)(xv.y * i1 * wv.y);
  o[2] = (_Float16)(xv.z * i2 * wv.z);
  o[3] = (_Float16)(xv.w * i3 * wv.w);
  *(f16x4*)(xn + (size_t)tid * 4) = o;
}

// ---------- weight conversion f32 -> f16 ----------
__global__ __launch_bounds__(256)
void convw(const float* __restrict__ wq, const float* __restrict__ wk,
           const float* __restrict__ wv, const float* __restrict__ wo,
           ushort_t* __restrict__ bqkv, ushort_t* __restrict__ bwo) {
  int tid = blockIdx.x * 256 + threadIdx.x;   // 589824/4 threads
  float4 a = ((const float4*)wq)[tid];
  float4 b = ((const float4*)wk)[tid];
  float4 c = ((const float4*)wv)[tid];
  float4 d = ((const float4*)wo)[tid];
  f16x4 pa, pb, pc, pd;
  pa[0]=(_Float16)a.x; pa[1]=(_Float16)a.y; pa[2]=(_Float16)a.z; pa[3]=(_Float16)a.w;
  pb[0]=(_Float16)b.x; pb[1]=(_Float16)b.y; pb[2]=(_Float16)b.z; pb[3]=(_Float16)b.w;
  pc[0]=(_Float16)c.x; pc[1]=(_Float16)c.y; pc[2]=(_Float16)c.z; pc[3]=(_Float16)c.w;
  pd[0]=(_Float16)d.x; pd[1]=(_Float16)d.y; pd[2]=(_Float16)d.z; pd[3]=(_Float16)d.w;
  ((f16x4*)bqkv)[tid]             = pa;
  ((f16x4*)(bqkv + 589824))[tid]  = pb;
  ((f16x4*)(bqkv + 1179648))[tid] = pc;
  ((f16x4*)bwo)[tid]              = pd;
}

// ---------- GEMM: out[m][n] = sum_k A[m][k]*B[n][k] (+bias) ----------
// MODE 0: N=2304 -> scatter Q (scaled 0.125*log2e), K, V^T kv-permuted (f16)
// MODE 1: N=768  -> d_out fp32 row-major
template <int MODE>
__global__ __launch_bounds__(256)
void gemm_f16(const ushort_t* __restrict__ A, const ushort_t* __restrict__ B,
              const float* __restrict__ b0, const float* __restrict__ b1,
              const float* __restrict__ b2,
              ushort_t* __restrict__ q, ushort_t* __restrict__ k,
              ushort_t* __restrict__ v, float* __restrict__ outf, int nbn) {
  __shared__ __align__(16) ushort_t As[128 * 32];
  __shared__ __align__(16) ushort_t Bs[128 * 32];

  const int bid = blockIdx.x;
  const int bm = bid / nbn, bn = bid % nbn;
  const int tid = threadIdx.x;
  const int w = tid >> 6, l = tid & 63;
  const int wr = w >> 1, wc = w & 1;
  const int lr = l & 15, lg = l >> 4;

  f32x4 acc[4][4] = {};

  const ushort_t* Ab = A + (size_t)bm * 128 * 768;
  const ushort_t* Bb = B + (size_t)bn * 128 * 768;
  const int srow = w * 32 + (l >> 2);
  const int scol = (l & 3) * 8;

  for (int kt = 0; kt < 24; ++kt) {
    const int k0 = kt * 32;
    gload_lds16(Ab + (size_t)srow * 768 + k0 + scol,        As + (w * 32) * 32);
    gload_lds16(Ab + (size_t)(srow + 16) * 768 + k0 + scol, As + (w * 32 + 16) * 32);
    gload_lds16(Bb + (size_t)srow * 768 + k0 + scol,        Bs + (w * 32) * 32);
    gload_lds16(Bb + (size_t)(srow + 16) * 768 + k0 + scol, Bs + (w * 32 + 16) * 32);
    __syncthreads();
    f16x8 af[4], bf[4];
#pragma unroll
    for (int r = 0; r < 4; ++r)
      af[r] = *(const f16x8*)(As + (wr * 64 + r * 16 + lr) * 32 + lg * 8);
#pragma unroll
    for (int c = 0; c < 4; ++c)
      bf[c] = *(const f16x8*)(Bs + (wc * 64 + c * 16 + lr) * 32 + lg * 8);
#pragma unroll
    for (int r = 0; r < 4; ++r)
#pragma unroll
      for (int c = 0; c < 4; ++c)
        acc[r][c] = __builtin_amdgcn_mfma_f32_16x16x32_f16(af[r], bf[c], acc[r][c], 0, 0, 0);
    __syncthreads();
  }

  // epilogue. C/D layout: col = lane&15, row = (lane>>4)*4 + reg  [m89/m91]
#pragma unroll
  for (int r = 0; r < 4; ++r) {
#pragma unroll
    for (int c = 0; c < 4; ++c) {
      const int n = bn * 128 + wc * 64 + c * 16 + lr;
      const int mbase = bm * 128 + wr * 64 + r * 16 + lg * 4;
      if (MODE == 0) {
        const int region = n / 768;          // uniform per block (768%128==0)
        const int nn = n - region * 768;
        const int hh = nn >> 6, hd = nn & 63;
        const float bb = (region == 0 ? b0 : region == 1 ? b1 : b2)[nn];
        if (region == 2) {
          // V^T with kv-permuted columns: token s -> column tile*64 + sigma^{-1}(s&63),
          // so PV's B-frag k-slot ordering matches P's in-register layout.
          const int bi = mbase >> 10, s0 = mbase & 1023;
          const int tile = s0 >> 6, q6 = s0 & 63;
          const int aa = q6 >> 5, r5 = q6 & 31;
          const int t1 = r5 >> 3, h2 = (r5 >> 2) & 1;
          const int g = t1 >> 1, j = (2 * t1) & 3;
          const int s0p = (tile << 6) + (((aa << 1) + g) << 4) + (h2 << 3) + 2 * j;
          f16x4 pv;
#pragma unroll
          for (int gi = 0; gi < 4; ++gi) pv[gi] = (_Float16)(acc[r][c][gi] + bb);
          *(f16x4*)(v + (((size_t)(bi * 12 + hh)) * 64 + hd) * 1024 + s0p) = pv;
        } else {
#pragma unroll
          for (int gi = 0; gi < 4; ++gi) {
            const int m = mbase + gi;
            const int bi = m >> 10, s = m & 1023;
            const float val = acc[r][c][gi] + bb;
            if (region == 0)
              q[(((size_t)(bi * 12 + hh)) * 1024 + s) * 64 + hd] = f2h(val * (0.125f * LOG2E));
            else
              k[(((size_t)(bi * 12 + hh)) * 1024 + s) * 64 + hd] = f2h(val);
          }
        }
      } else {
        const float bb = b0[n];
#pragma unroll
        for (int gi = 0; gi < 4; ++gi) {
          const int m = mbase + gi;
          outf[(size_t)m * 768 + n] = acc[r][c][gi] + bb;
        }
      }
    }
  }
}

// ---------- fused flash attention v4: LDS-staged, 4 waves, 3 blocks/CU ----------
// qb: [96][1024][64] f16 (scaled 0.125*log2e), kb: [96][1024][64] f16,
// vt: [96][64][1024] f16 with kv-permuted columns per 64-tile.
// Block = 4 waves x 32 q-rows = 128 q-rows; K/V tiles (8KB each) staged via
// global_load_lds, double-buffered (32KB); one __syncthreads per kv-tile.
// Grid 768 = exactly 3 blocks/CU -> barrier drains overlap across blocks.
__global__ __launch_bounds__(256, 3)
void attn_fused4(const ushort_t* __restrict__ qb, const ushort_t* __restrict__ kb,
                 const ushort_t* __restrict__ vt, ushort_t* __restrict__ ao) {
  __shared__ __align__(16) ushort_t smem[16384];  // K dbuf 16KB + V dbuf 16KB
  const int tid = threadIdx.x;
  const int w = tid >> 6, l = tid & 63;
  const int lq = l & 31, hi = l >> 5;

  // XCD-contiguous remap: 96 consecutive cids per XCD = 12 heads x 8 q-tiles
  const int bid = blockIdx.x;
  const int cid = (bid & 7) * 96 + (bid >> 3);
  const int bh = cid >> 3, qt = cid & 7;
  const int b = bh / 12, h = bh % 12;

  const ushort_t* qp = qb + ((size_t)bh * 1024 + qt * 128 + w * 32) * 64;
  const ushort_t* kp = kb + (size_t)bh * 65536;
  const ushort_t* vp = vt + (size_t)bh * 65536;

  // Q B-frags: col q = lq, k = kc*16 + hi*8 + i
  f16x8 qf[4];
#pragma unroll
  for (int kc = 0; kc < 4; ++kc)
    qf[kc] = *(const f16x8*)(qp + lq * 64 + kc * 16 + hi * 8);

  // staging: 8KB tile = 512 x 16B chunks; thread covers chunks tid and tid+256.
  // chunk c: row = c>>3, slot = c&7; source col pre-swizzled (rule 21).
  const int r1 = tid >> 3,          s1 = (tid & 7) ^ (r1 & 7);
  const int r2 = (tid + 256) >> 3,  s2 = (tid & 7) ^ (r2 & 7);
  char* Kl0 = (char*)smem + w * 1024;            // chunk tid dest (lane-linear)
  char* Kl1 = (char*)smem + 4096 + w * 1024;     // chunk tid+256 dest
  char* Vl0 = (char*)smem + 16384 + w * 1024;
  char* Vl1 = (char*)smem + 16384 + 4096 + w * 1024;

  f32x16 oacc0 = {}, oacc1 = {};
  float mrun = -1e30f;
  float lr0 = 0.f, lr1 = 0.f, lr2 = 0.f, lr3 = 0.f;

  // prologue: stage tile 0 into buf 0
  gload_lds16(kp + (size_t)r1 * 64 + s1 * 8,          Kl0);
  gload_lds16(kp + (size_t)r2 * 64 + s2 * 8,          Kl1);
  gload_lds16(vp + (size_t)r1 * 1024 + s1 * 8,        Vl0);
  gload_lds16(vp + (size_t)r2 * 1024 + s2 * 8,        Vl1);
  __syncthreads();

  int buf = 0;
  const int cswz = lq & 7;
  for (int t = 0; t < 16; ++t) {
    if (t < 15) {
      const int kv0n = (t + 1) << 6;
      const int off = (buf ^ 1) * 8192;
      gload_lds16(kp + (size_t)(kv0n + r1) * 64 + s1 * 8,  Kl0 + off);
      gload_lds16(kp + (size_t)(kv0n + r2) * 64 + s2 * 8,  Kl1 + off);
      gload_lds16(vp + (size_t)r1 * 1024 + kv0n + s1 * 8,  Vl0 + off);
      gload_lds16(vp + (size_t)r2 * 1024 + kv0n + s2 * 8,  Vl1 + off);
    }
    const char* kbase = (const char*)smem + buf * 8192;
    const char* vbase = (const char*)smem + 16384 + buf * 8192;

    f16x8 ka0[4], ka1[4];
#pragma unroll
    for (int kc = 0; kc < 4; ++kc) {
      ka0[kc] = *(const f16x8*)(kbase + lq * 128 + (((kc * 2 + hi) ^ cswz) * 16));
      ka1[kc] = *(const f16x8*)(kbase + (32 + lq) * 128 + (((kc * 2 + hi) ^ cswz) * 16));
    }
    f32x16 s0v = {}, s1v = {};
    __builtin_amdgcn_s_setprio(1);
#pragma unroll
    for (int kc = 0; kc < 4; ++kc) {
      s0v = __builtin_amdgcn_mfma_f32_32x32x16_f16(ka0[kc], qf[kc], s0v, 0, 0, 0);
      s1v = __builtin_amdgcn_mfma_f32_32x32x16_f16(ka1[kc], qf[kc], s1v, 0, 0, 0);
    }
    __builtin_amdgcn_s_setprio(0);

    // V frags issued before softmax so ds_read latency hides under VALU
    f16x8 va0[4], va1[4];
#pragma unroll
    for (int c = 0; c < 4; ++c) {
      va0[c] = *(const f16x8*)(vbase + lq * 128 + (((c * 2 + hi) ^ cswz) * 16));
      va1[c] = *(const f16x8*)(vbase + (32 + lq) * 128 + (((c * 2 + hi) ^ cswz) * 16));
    }

    // ---- online softmax, lane-local, defer-max (T13) ----
    float mt = -1e30f;
#pragma unroll
    for (int r = 0; r < 16; ++r) mt = fmaxf(mt, fmaxf(s0v[r], s1v[r]));
    mt = fmaxf(mt, __shfl_xor(mt, 32, 64));   // combine hi halves of q-column
    if (__any(mt > mrun + 8.f)) {
      const float mnew = fmaxf(mrun, mt);
      const float corr = __builtin_exp2f(mrun - mnew);
      lr0 *= corr; lr1 *= corr; lr2 *= corr; lr3 *= corr;
#pragma unroll
      for (int r = 0; r < 16; ++r) { oacc0[r] *= corr; oacc1[r] *= corr; }
      mrun = mnew;
    }

    float e0[16], e1[16];
#pragma unroll
    for (int r = 0; r < 16; ++r) {
      e0[r] = __builtin_exp2f(s0v[r] - mrun);
      e1[r] = __builtin_exp2f(s1v[r] - mrun);
    }
#pragma unroll
    for (int r = 0; r < 8; ++r) {
      lr0 += e0[r]; lr1 += e0[r + 8];
      lr2 += e1[r]; lr3 += e1[r + 8];
    }
    uint_t pk0[8], pk1[8];
#pragma unroll
    for (int tt = 0; tt < 8; ++tt) {
      pk0[tt] = packpair(e0[2 * tt], e0[2 * tt + 1]);
      pk1[tt] = packpair(e1[2 * tt], e1[2 * tt + 1]);
    }
    const f16x8 pb0 = mk8(pk0[0], pk0[1], pk0[2], pk0[3]);
    const f16x8 pb1 = mk8(pk0[4], pk0[5], pk0[6], pk0[7]);
    const f16x8 pb2 = mk8(pk1[0], pk1[1], pk1[2], pk1[3]);
    const f16x8 pb3 = mk8(pk1[4], pk1[5], pk1[6], pk1[7]);

    __builtin_amdgcn_s_setprio(1);
    oacc0 = __builtin_amdgcn_mfma_f32_32x32x16_f16(va0[0], pb0, oacc0, 0, 0, 0);
    oacc1 = __builtin_amdgcn_mfma_f32_32x32x16_f16(va1[0], pb0, oacc1, 0, 0, 0);
    oacc0 = __builtin_amdgcn_mfma_f32_32x32x16_f16(va0[1], pb1, oacc0, 0, 0, 0);
    oacc1 = __builtin_amdgcn_mfma_f32_32x32x16_f16(va1[1], pb1, oacc1, 0, 0, 0);
    oacc0 = __builtin_amdgcn_mfma_f32_32x32x16_f16(va0[2], pb2, oacc0, 0, 0, 0);
    oacc1 = __builtin_amdgcn_mfma_f32_32x32x16_f16(va1[2], pb2, oacc1, 0, 0, 0);
    oacc0 = __builtin_amdgcn_mfma_f32_32x32x16_f16(va0[3], pb3, oacc0, 0, 0, 0);
    oacc1 = __builtin_amdgcn_mfma_f32_32x32x16_f16(va1[3], pb3, oacc1, 0, 0, 0);
    __builtin_amdgcn_s_setprio(0);

    __syncthreads();    // drains vmcnt (stage) + lgkm; protects buf swap
    buf ^= 1;
  }

  // ---- finalize l across hi halves (single cross-lane op) ----
  float lrun = (lr0 + lr1) + (lr2 + lr3);
  lrun += __shfl_xor(lrun, 32, 64);
  const float invl = 1.0f / lrun;

  // ---- epilogue: O^T -> swizzled LDS -> coalesced global f16 rows ----
  uint_t* ot = (uint_t*)smem + w * 1024 + lq * 32;   // wave-private 4KB tile
#pragma unroll
  for (int tt = 0; tt < 8; ++tt) {
    const int base = (tt & 1) + ((tt >> 1) << 2) + 2 * hi;
    ot[base ^ lq]        = packpair(oacc0[2 * tt] * invl, oacc0[2 * tt + 1] * invl);
    ot[(base + 16) ^ lq] = packpair(oacc1[2 * tt] * invl, oacc1[2 * tt + 1] * invl);
  }
  __syncthreads();
  const int row = tid >> 1, halfc = tid & 1;        // row 0..127
  const int w2 = row >> 5, qq = row & 31;
  const uint_t* srcp = (const uint_t*)smem + w2 * 1024 + qq * 32;
  ushort_t* dst = ao + (size_t)(b * 1024 + qt * 128 + row) * 768 + h * 64 + halfc * 32;
#pragma unroll
  for (int jj = 0; jj < 4; ++jj) {
    u32x4 tv;
#pragma unroll
    for (int i2 = 0; i2 < 4; ++i2)
      tv[i2] = srcp[(halfc * 16 + jj * 4 + i2) ^ qq];
    *(u32x4*)(dst + jj * 8) = tv;
  }
}

// ---------- launch ----------
extern "C" void kernel_launch(void* const* d_in, const int* in_sizes, int n_in,
                              void* d_out, int out_size, void* d_ws, size_t ws_size,
                              hipStream_t stream) {
  const float* x  = (const float*)d_in[0];
  const float* nw = (const float*)d_in[1];
  const float* wq = (const float*)d_in[2];
  const float* bq = (const float*)d_in[3];
  const float* wk = (const float*)d_in[4];
  const float* bk = (const float*)d_in[5];
  const float* wv = (const float*)d_in[6];
  const float* bv = (const float*)d_in[7];
  const float* wo = (const float*)d_in[8];
  const float* bo = (const float*)d_in[9];
  float* out = (float*)d_out;

  char* ws = (char*)d_ws;
  // tmp (12.58MB f16) is consumed by lrn_b, then its region is reused for qbuf.
  ushort_t* tmp   = (ushort_t*)ws;
  ushort_t* qbuf  = (ushort_t*)(ws);
  ushort_t* kbuf  = (ushort_t*)(ws + 12582912);
  ushort_t* xn    = (ushort_t*)(ws + 25165824);   // 12,582,912
  ushort_t* bwqkv = (ushort_t*)(ws + 37748736);   //  3,538,944
  ushort_t* bwo   = (ushort_t*)(ws + 41287680);   //  1,179,648
  ushort_t* vtb   = (ushort_t*)(ws + 42467328);   // 12,582,912
  ushort_t* aout  = (ushort_t*)(ws + 55050240);   // 12,582,912  (total 67,633,152)

  lrn_a<<<6144, 256, 0, stream>>>(x, tmp);
  lrn_b<<<6144, 256, 0, stream>>>(x, tmp, nw, xn);
  convw<<<576, 256, 0, stream>>>(wq, wk, wv, wo, bwqkv, bwo);
  gemm_f16<0><<<64 * 18, 256, 0, stream>>>(xn, bwqkv, bq, bk, bv,
                                           qbuf, kbuf, vtb, nullptr, 18);
  attn_fused4<<<768, 256, 0, stream>>>(qbuf, kbuf, vtb, aout);
  gemm_f16<1><<<64 * 6, 256, 0, stream>>>(aout, bwo, bo, nullptr, nullptr, nullptr,
                                          nullptr, nullptr, out, 6);
}

// Round 5
// 163.415 us; speedup vs baseline: 1.2486x; 1.0151x over previous
//
#include <hip/hip_runtime.h>

// ---------- types ----------
typedef _Float16 f16x8 __attribute__((ext_vector_type(8)));
typedef _Float16 f16x4 __attribute__((ext_vector_type(4)));
typedef _Float16 f16x2 __attribute__((ext_vector_type(2)));
typedef float    f32x4 __attribute__((ext_vector_type(4)));
typedef float    f32x16 __attribute__((ext_vector_type(16)));
typedef unsigned int u32x4 __attribute__((ext_vector_type(4)));
typedef unsigned short ushort_t;
typedef unsigned int uint_t;

#define LOG2E 1.44269504088896340736f

__device__ __forceinline__ ushort_t f2h(float x) {
  _Float16 h = (_Float16)x;
  return __builtin_bit_cast(ushort_t, h);
}

__device__ __forceinline__ uint_t packpair(float a, float b) {
  return __builtin_bit_cast(uint_t, __builtin_amdgcn_cvt_pkrtz(a, b));
}

__device__ __forceinline__ f16x8 mk8(uint_t a, uint_t b, uint_t c, uint_t d) {
  u32x4 t; t[0] = a; t[1] = b; t[2] = c; t[3] = d;
  return __builtin_bit_cast(f16x8, t);
}

// async global->LDS, 16B per lane. LDS dest is wave-uniform base + lane*16.
__device__ __forceinline__ void gload_lds16(const void* g, void* lds) {
  __builtin_amdgcn_global_load_lds(
      (const __attribute__((address_space(1))) void*)(uintptr_t)g,
      (__attribute__((address_space(3))) void*)(unsigned)(uintptr_t)lds,
      16, 0, 0);
}

// ---------- LocalRmsNorm: pass A (horizontal 7-tap box of x^2) -> f16 tmp ----------
__global__ __launch_bounds__(256)
void lrn_a(const float* __restrict__ x, ushort_t* __restrict__ tmp) {
  int tid = blockIdx.x * 256 + threadIdx.x;     // 8*1024*192 threads
  int dv  = tid % 192;
  int rem = tid / 192;
  int pos = rem & 1023;
  int b   = rem >> 10;
  int r = pos >> 5, c = pos & 31;
  const float4* base = (const float4*)x + ((size_t)b * 1024 + (size_t)r * 32) * 192 + dv;
  float ax = 0.f, ay = 0.f, az = 0.f, aw = 0.f;
#pragma unroll
  for (int dc = -3; dc <= 3; ++dc) {
    int cc = c + dc;
    if (cc >= 0 && cc < 32) {
      float4 v = base[cc * 192];
      ax += v.x * v.x; ay += v.y * v.y; az += v.z * v.z; aw += v.w * v.w;
    }
  }
  f16x4 o;
  o[0] = (_Float16)ax; o[1] = (_Float16)ay; o[2] = (_Float16)az; o[3] = (_Float16)aw;
  *(f16x4*)(tmp + (size_t)tid * 4) = o;
}

// ---------- LocalRmsNorm: pass B (vertical 7-tap) -> xn (f16) ----------
__global__ __launch_bounds__(256)
void lrn_b(const float* __restrict__ x, const ushort_t* __restrict__ tmp,
           const float* __restrict__ wn, ushort_t* __restrict__ xn) {
  int tid = blockIdx.x * 256 + threadIdx.x;
  int dv  = tid % 192;
  int rem = tid / 192;
  int pos = rem & 1023;
  int b   = rem >> 10;
  int r = pos >> 5, c = pos & 31;
  const ushort_t* tb = tmp + (((size_t)b * 1024 + c) * 192 + dv) * 4;
  float ax = 0.f, ay = 0.f, az = 0.f, aw = 0.f;
#pragma unroll
  for (int dr = -3; dr <= 3; ++dr) {
    int rr = r + dr;
    if (rr >= 0 && rr < 32) {
      f16x4 v = *(const f16x4*)(tb + (size_t)rr * 24576);
      ax += (float)v[0]; ay += (float)v[1]; az += (float)v[2]; aw += (float)v[3];
    }
  }
  float4 xv = ((const float4*)x)[tid];
  float4 wv = ((const float4*)wn)[dv];
  const float inv49 = 1.0f / 49.0f;
  float i0 = 1.0f / sqrtf(1e-7f + ax * inv49);
  float i1 = 1.0f / sqrtf(1e-7f + ay * inv49);
  float i2 = 1.0f / sqrtf(1e-7f + az * inv49);
  float i3 = 1.0f / sqrtf(1e-7f + aw * inv49);
  f16x4 o;
  o[0] = (_Float16)(xv.x * i0 * wv.x);
  o[1] = (_Float16)(xv.y * i1 * wv.y);
  o[2] = (_Float16)(xv.z * i2 * wv.z);
  o[3] = (_Float16)(xv.w * i3 * wv.w);
  *(f16x4*)(xn + (size_t)tid * 4) = o;
}

// ---------- weight conversion f32 -> f16 ----------
__global__ __launch_bounds__(256)
void convw(const float* __restrict__ wq, const float* __restrict__ wk,
           const float* __restrict__ wv, const float* __restrict__ wo,
           ushort_t* __restrict__ bqkv, ushort_t* __restrict__ bwo) {
  int tid = blockIdx.x * 256 + threadIdx.x;   // 589824/4 threads
  float4 a = ((const float4*)wq)[tid];
  float4 b = ((const float4*)wk)[tid];
  float4 c = ((const float4*)wv)[tid];
  float4 d = ((const float4*)wo)[tid];
  f16x4 pa, pb, pc, pd;
  pa[0]=(_Float16)a.x; pa[1]=(_Float16)a.y; pa[2]=(_Float16)a.z; pa[3]=(_Float16)a.w;
  pb[0]=(_Float16)b.x; pb[1]=(_Float16)b.y; pb[2]=(_Float16)b.z; pb[3]=(_Float16)b.w;
  pc[0]=(_Float16)c.x; pc[1]=(_Float16)c.y; pc[2]=(_Float16)c.z; pc[3]=(_Float16)c.w;
  pd[0]=(_Float16)d.x; pd[1]=(_Float16)d.y; pd[2]=(_Float16)d.z; pd[3]=(_Float16)d.w;
  ((f16x4*)bqkv)[tid]             = pa;
  ((f16x4*)(bqkv + 589824))[tid]  = pb;
  ((f16x4*)(bqkv + 1179648))[tid] = pc;
  ((f16x4*)bwo)[tid]              = pd;
}

// ---------- GEMM: out[m][n] = sum_k A[m][k]*B[n][k] (+bias) ----------
// Double-buffered LDS (stage k+1 || compute k, ONE barrier/iter), slot-swizzled
// LDS (4-way instead of 8-way bank conflict), XCD-contiguous block remap.
// MODE 0: N=2304 -> scatter Q (scaled 0.125*log2e), K, V^T kv-permuted (f16)
// MODE 1: N=768  -> d_out fp32 row-major
#define GSTAGE(BUF, KT) do {                                                      \
    const int k0_ = (KT) * 32;                                                    \
    gload_lds16(Ab + (size_t)srow * 768 + k0_ + scols,        As[BUF] + w * 1024);\
    gload_lds16(Ab + (size_t)(srow + 16) * 768 + k0_ + scols, As[BUF] + w * 1024 + 512); \
    gload_lds16(Bb + (size_t)srow * 768 + k0_ + scols,        Bs[BUF] + w * 1024);\
    gload_lds16(Bb + (size_t)(srow + 16) * 768 + k0_ + scols, Bs[BUF] + w * 1024 + 512); \
  } while (0)

#define GEMM_TILE(KT, CUR, NXT) do {                                              \
    if ((KT) + 1 < 24) GSTAGE(NXT, (KT) + 1);                                     \
    f16x8 af[4], bf[4];                                                           \
    _Pragma("unroll")                                                             \
    for (int r = 0; r < 4; ++r)                                                   \
      af[r] = *(const f16x8*)(As[CUR] + (wr * 64 + r * 16 + lr) * 32 + colsw);    \
    _Pragma("unroll")                                                             \
    for (int c = 0; c < 4; ++c)                                                   \
      bf[c] = *(const f16x8*)(Bs[CUR] + (wc * 64 + c * 16 + lr) * 32 + colsw);    \
    _Pragma("unroll")                                                             \
    for (int r = 0; r < 4; ++r)                                                   \
      _Pragma("unroll")                                                           \
      for (int c = 0; c < 4; ++c)                                                 \
        acc[r][c] = __builtin_amdgcn_mfma_f32_16x16x32_f16(af[r], bf[c], acc[r][c], 0, 0, 0); \
    __syncthreads();                                                              \
  } while (0)

template <int MODE>
__global__ __launch_bounds__(256)
void gemm_f16(const ushort_t* __restrict__ A, const ushort_t* __restrict__ B,
              const float* __restrict__ b0, const float* __restrict__ b1,
              const float* __restrict__ b2,
              ushort_t* __restrict__ q, ushort_t* __restrict__ k,
              ushort_t* __restrict__ v, float* __restrict__ outf, int nbn) {
  __shared__ __align__(16) ushort_t As[2][128 * 32];   // 2 x 8KB
  __shared__ __align__(16) ushort_t Bs[2][128 * 32];   // 2 x 8KB

  // XCD-contiguous remap: each XCD gets 8 consecutive m-panels x all n
  const int nwg = gridDim.x;
  const int bid = blockIdx.x;
  const int cid = (bid & 7) * (nwg >> 3) + (bid >> 3);
  const int bm = cid / nbn, bn = cid % nbn;
  const int tid = threadIdx.x;
  const int w = tid >> 6, l = tid & 63;
  const int wr = w >> 1, wc = w & 1;
  const int lr = l & 15, lg = l >> 4;

  f32x4 acc[4][4] = {};

  const ushort_t* Ab = A + (size_t)bm * 128 * 768;
  const ushort_t* Bb = B + (size_t)bn * 128 * 768;
  const int srow = w * 32 + (l >> 2);
  // source slot swizzled so LDS[R][s] = G[R][s ^ (R&3)]  (rule 21 both-sides)
  const int scols = (((l & 3) ^ ((l >> 2) & 3))) * 8;
  // read col for logical slot lg of row R: (lg ^ (R&3))*8 ; R ≡ lr (mod 4)
  const int colsw = (lg ^ (lr & 3)) * 8;

  GSTAGE(0, 0);
  __syncthreads();
  for (int kt = 0; kt < 24; kt += 2) {
    GEMM_TILE(kt, 0, 1);
    GEMM_TILE(kt + 1, 1, 0);
  }

  // epilogue. C/D layout: col = lane&15, row = (lane>>4)*4 + reg  [m89/m91]
#pragma unroll
  for (int r = 0; r < 4; ++r) {
#pragma unroll
    for (int c = 0; c < 4; ++c) {
      const int n = bn * 128 + wc * 64 + c * 16 + lr;
      const int mbase = bm * 128 + wr * 64 + r * 16 + lg * 4;
      if (MODE == 0) {
        const int region = n / 768;          // uniform per block (768%128==0)
        const int nn = n - region * 768;
        const int hh = nn >> 6, hd = nn & 63;
        const float bb = (region == 0 ? b0 : region == 1 ? b1 : b2)[nn];
        if (region == 2) {
          // V^T with kv-permuted columns: token s -> column tile*64 + sigma^{-1}(s&63),
          // so PV's B-frag k-slot ordering matches P's in-register layout.
          const int bi = mbase >> 10, s0 = mbase & 1023;
          const int tile = s0 >> 6, q6 = s0 & 63;
          const int aa = q6 >> 5, r5 = q6 & 31;
          const int t1 = r5 >> 3, h2 = (r5 >> 2) & 1;
          const int g = t1 >> 1, j = (2 * t1) & 3;
          const int s0p = (tile << 6) + (((aa << 1) + g) << 4) + (h2 << 3) + 2 * j;
          f16x4 pv;
#pragma unroll
          for (int gi = 0; gi < 4; ++gi) pv[gi] = (_Float16)(acc[r][c][gi] + bb);
          *(f16x4*)(v + (((size_t)(bi * 12 + hh)) * 64 + hd) * 1024 + s0p) = pv;
        } else {
#pragma unroll
          for (int gi = 0; gi < 4; ++gi) {
            const int m = mbase + gi;
            const int bi = m >> 10, s = m & 1023;
            const float val = acc[r][c][gi] + bb;
            if (region == 0)
              q[(((size_t)(bi * 12 + hh)) * 1024 + s) * 64 + hd] = f2h(val * (0.125f * LOG2E));
            else
              k[(((size_t)(bi * 12 + hh)) * 1024 + s) * 64 + hd] = f2h(val);
          }
        }
      } else {
        const float bb = b0[n];
#pragma unroll
        for (int gi = 0; gi < 4; ++gi) {
          const int m = mbase + gi;
          outf[(size_t)m * 768 + n] = acc[r][c][gi] + bb;
        }
      }
    }
  }
}

// ---------- fused flash attention v5: LDS dbuf, unroll-2, fdot2 row-sums ----------
// qb: [96][1024][64] f16 (scaled 0.125*log2e), kb: [96][1024][64] f16,
// vt: [96][64][1024] f16 with kv-permuted columns per 64-tile.
#define ATILE(T, CUR, NXT) do {                                                   \
    if ((T) < 15) {                                                               \
      const int kv0n = ((T) + 1) << 6;                                            \
      gload_lds16(kp + (size_t)(kv0n + r1) * 64 + s1 * 8,  Kl0 + (NXT) * 8192);   \
      gload_lds16(kp + (size_t)(kv0n + r2) * 64 + s2 * 8,  Kl1 + (NXT) * 8192);   \
      gload_lds16(vp + (size_t)r1 * 1024 + kv0n + s1 * 8,  Vl0 + (NXT) * 8192);   \
      gload_lds16(vp + (size_t)r2 * 1024 + kv0n + s2 * 8,  Vl1 + (NXT) * 8192);   \
    }                                                                             \
    const char* kbase = (const char*)smem + (CUR) * 8192;                         \
    const char* vbase = (const char*)smem + 16384 + (CUR) * 8192;                 \
    f16x8 ka0[4], ka1[4];                                                         \
    _Pragma("unroll")                                                             \
    for (int kc = 0; kc < 4; ++kc) {                                              \
      ka0[kc] = *(const f16x8*)(kbase + off[kc]);                                 \
      ka1[kc] = *(const f16x8*)(kbase + off[kc] + 4096);                          \
    }                                                                             \
    f32x16 s0v = {}, s1v = {};                                                    \
    __builtin_amdgcn_s_setprio(1);                                                \
    _Pragma("unroll")                                                             \
    for (int kc = 0; kc < 4; ++kc) {                                              \
      s0v = __builtin_amdgcn_mfma_f32_32x32x16_f16(ka0[kc], qf[kc], s0v, 0, 0, 0);\
      s1v = __builtin_amdgcn_mfma_f32_32x32x16_f16(ka1[kc], qf[kc], s1v, 0, 0, 0);\
    }                                                                             \
    __builtin_amdgcn_s_setprio(0);                                                \
    f16x8 va0[4], va1[4];                                                         \
    _Pragma("unroll")                                                             \
    for (int c = 0; c < 4; ++c) {                                                 \
      va0[c] = *(const f16x8*)(vbase + off[c]);                                   \
      va1[c] = *(const f16x8*)(vbase + off[c] + 4096);                            \
    }                                                                             \
    float mt = -1e30f;                                                            \
    _Pragma("unroll")                                                             \
    for (int r = 0; r < 16; ++r) mt = fmaxf(mt, fmaxf(s0v[r], s1v[r]));           \
    mt = fmaxf(mt, __shfl_xor(mt, 32, 64));                                       \
    if (__any(mt > mrun + 8.f)) {                                                 \
      const float mnew = fmaxf(mrun, mt);                                         \
      const float corr = __builtin_exp2f(mrun - mnew);                            \
      lr0 *= corr; lr1 *= corr; lr2 *= corr; lr3 *= corr;                         \
      _Pragma("unroll")                                                           \
      for (int r = 0; r < 16; ++r) { oacc0[r] *= corr; oacc1[r] *= corr; }        \
      mrun = mnew;                                                                \
    }                                                                             \
    uint_t pk0[8], pk1[8];                                                        \
    _Pragma("unroll")                                                             \
    for (int tt = 0; tt < 8; ++tt) {                                              \
      pk0[tt] = packpair(__builtin_exp2f(s0v[2 * tt] - mrun),                     \
                         __builtin_exp2f(s0v[2 * tt + 1] - mrun));                \
      pk1[tt] = packpair(__builtin_exp2f(s1v[2 * tt] - mrun),                     \
                         __builtin_exp2f(s1v[2 * tt + 1] - mrun));                \
    }                                                                             \
    _Pragma("unroll")                                                             \
    for (int tt = 0; tt < 4; ++tt) {                                              \
      lr0 = __builtin_amdgcn_fdot2(__builtin_bit_cast(f16x2, pk0[tt]),     one2, lr0, false); \
      lr1 = __builtin_amdgcn_fdot2(__builtin_bit_cast(f16x2, pk0[tt + 4]), one2, lr1, false); \
      lr2 = __builtin_amdgcn_fdot2(__builtin_bit_cast(f16x2, pk1[tt]),     one2, lr2, false); \
      lr3 = __builtin_amdgcn_fdot2(__builtin_bit_cast(f16x2, pk1[tt + 4]), one2, lr3, false); \
    }                                                                             \
    const f16x8 pb0 = mk8(pk0[0], pk0[1], pk0[2], pk0[3]);                        \
    const f16x8 pb1 = mk8(pk0[4], pk0[5], pk0[6], pk0[7]);                        \
    const f16x8 pb2 = mk8(pk1[0], pk1[1], pk1[2], pk1[3]);                        \
    const f16x8 pb3 = mk8(pk1[4], pk1[5], pk1[6], pk1[7]);                        \
    __builtin_amdgcn_s_setprio(1);                                                \
    oacc0 = __builtin_amdgcn_mfma_f32_32x32x16_f16(va0[0], pb0, oacc0, 0, 0, 0);  \
    oacc1 = __builtin_amdgcn_mfma_f32_32x32x16_f16(va1[0], pb0, oacc1, 0, 0, 0);  \
    oacc0 = __builtin_amdgcn_mfma_f32_32x32x16_f16(va0[1], pb1, oacc0, 0, 0, 0);  \
    oacc1 = __builtin_amdgcn_mfma_f32_32x32x16_f16(va1[1], pb1, oacc1, 0, 0, 0);  \
    oacc0 = __builtin_amdgcn_mfma_f32_32x32x16_f16(va0[2], pb2, oacc0, 0, 0, 0);  \
    oacc1 = __builtin_amdgcn_mfma_f32_32x32x16_f16(va1[2], pb2, oacc1, 0, 0, 0);  \
    oacc0 = __builtin_amdgcn_mfma_f32_32x32x16_f16(va0[3], pb3, oacc0, 0, 0, 0);  \
    oacc1 = __builtin_amdgcn_mfma_f32_32x32x16_f16(va1[3], pb3, oacc1, 0, 0, 0);  \
    __builtin_amdgcn_s_setprio(0);                                                \
    __syncthreads();                                                              \
  } while (0)

__global__ __launch_bounds__(256, 3)
void attn_fused5(const ushort_t* __restrict__ qb, const ushort_t* __restrict__ kb,
                 const ushort_t* __restrict__ vt, ushort_t* __restrict__ ao) {
  __shared__ __align__(16) ushort_t smem[16384];  // K dbuf 16KB + V dbuf 16KB
  const int tid = threadIdx.x;
  const int w = tid >> 6, l = tid & 63;
  const int lq = l & 31, hi = l >> 5;

  // XCD-contiguous remap: 96 consecutive cids per XCD = 12 heads x 8 q-tiles
  const int bid = blockIdx.x;
  const int cid = (bid & 7) * 96 + (bid >> 3);
  const int bh = cid >> 3, qt = cid & 7;
  const int b = bh / 12, h = bh % 12;

  const ushort_t* qp = qb + ((size_t)bh * 1024 + qt * 128 + w * 32) * 64;
  const ushort_t* kp = kb + (size_t)bh * 65536;
  const ushort_t* vp = vt + (size_t)bh * 65536;

  // Q B-frags: col q = lq, k = kc*16 + hi*8 + i
  f16x8 qf[4];
#pragma unroll
  for (int kc = 0; kc < 4; ++kc)
    qf[kc] = *(const f16x8*)(qp + lq * 64 + kc * 16 + hi * 8);

  // staging: 8KB tile = 512 x 16B chunks; thread covers chunks tid and tid+256.
  const int r1 = tid >> 3,          s1 = (tid & 7) ^ (r1 & 7);
  const int r2 = (tid + 256) >> 3,  s2 = (tid & 7) ^ (r2 & 7);
  char* Kl0 = (char*)smem + w * 1024;
  char* Kl1 = (char*)smem + 4096 + w * 1024;
  char* Vl0 = (char*)smem + 16384 + w * 1024;
  char* Vl1 = (char*)smem + 16384 + 4096 + w * 1024;

  // loop-invariant swizzled ds_read byte offsets (K and V share the pattern)
  const int cswz = lq & 7;
  int off[4];
#pragma unroll
  for (int kc = 0; kc < 4; ++kc)
    off[kc] = lq * 128 + (((kc * 2 + hi) ^ cswz) * 16);

  f32x16 oacc0 = {}, oacc1 = {};
  float mrun = -1e30f;
  float lr0 = 0.f, lr1 = 0.f, lr2 = 0.f, lr3 = 0.f;
  const f16x2 one2 = {(_Float16)1.f, (_Float16)1.f};

  // prologue: stage tile 0 into buf 0
  gload_lds16(kp + (size_t)r1 * 64 + s1 * 8,   Kl0);
  gload_lds16(kp + (size_t)r2 * 64 + s2 * 8,   Kl1);
  gload_lds16(vp + (size_t)r1 * 1024 + s1 * 8, Vl0);
  gload_lds16(vp + (size_t)r2 * 1024 + s2 * 8, Vl1);
  __syncthreads();

  for (int t2 = 0; t2 < 16; t2 += 2) {
    ATILE(t2, 0, 1);
    ATILE(t2 + 1, 1, 0);
  }

  // ---- finalize l across hi halves (single cross-lane op) ----
  float lrun = (lr0 + lr1) + (lr2 + lr3);
  lrun += __shfl_xor(lrun, 32, 64);
  const float invl = 1.0f / lrun;

  // ---- epilogue: O^T -> swizzled LDS -> coalesced global f16 rows ----
  uint_t* ot = (uint_t*)smem + w * 1024 + lq * 32;   // wave-private 4KB tile
#pragma unroll
  for (int tt = 0; tt < 8; ++tt) {
    const int base = (tt & 1) + ((tt >> 1) << 2) + 2 * hi;
    ot[base ^ lq]        = packpair(oacc0[2 * tt] * invl, oacc0[2 * tt + 1] * invl);
    ot[(base + 16) ^ lq] = packpair(oacc1[2 * tt] * invl, oacc1[2 * tt + 1] * invl);
  }
  __syncthreads();
  const int row = tid >> 1, halfc = tid & 1;        // row 0..127
  const int w2 = row >> 5, qq = row & 31;
  const uint_t* srcp = (const uint_t*)smem + w2 * 1024 + qq * 32;
  ushort_t* dst = ao + (size_t)(b * 1024 + qt * 128 + row) * 768 + h * 64 + halfc * 32;
#pragma unroll
  for (int jj = 0; jj < 4; ++jj) {
    u32x4 tv;
#pragma unroll
    for (int i2 = 0; i2 < 4; ++i2)
      tv[i2] = srcp[(halfc * 16 + jj * 4 + i2) ^ qq];
    *(u32x4*)(dst + jj * 8) = tv;
  }
}

// ---------- launch ----------
extern "C" void kernel_launch(void* const* d_in, const int* in_sizes, int n_in,
                              void* d_out, int out_size, void* d_ws, size_t ws_size,
                              hipStream_t stream) {
  const float* x  = (const float*)d_in[0];
  const float* nw = (const float*)d_in[1];
  const float* wq = (const float*)d_in[2];
  const float* bq = (const float*)d_in[3];
  const float* wk = (const float*)d_in[4];
  const float* bk = (const float*)d_in[5];
  const float* wv = (const float*)d_in[6];
  const float* bv = (const float*)d_in[7];
  const float* wo = (const float*)d_in[8];
  const float* bo = (const float*)d_in[9];
  float* out = (float*)d_out;

  char* ws = (char*)d_ws;
  // tmp (12.58MB f16) is consumed by lrn_b, then its region is reused for qbuf.
  ushort_t* tmp   = (ushort_t*)ws;
  ushort_t* qbuf  = (ushort_t*)(ws);
  ushort_t* kbuf  = (ushort_t*)(ws + 12582912);
  ushort_t* xn    = (ushort_t*)(ws + 25165824);   // 12,582,912
  ushort_t* bwqkv = (ushort_t*)(ws + 37748736);   //  3,538,944
  ushort_t* bwo   = (ushort_t*)(ws + 41287680);   //  1,179,648
  ushort_t* vtb   = (ushort_t*)(ws + 42467328);   // 12,582,912
  ushort_t* aout  = (ushort_t*)(ws + 55050240);   // 12,582,912  (total 67,633,152)

  lrn_a<<<6144, 256, 0, stream>>>(x, tmp);
  lrn_b<<<6144, 256, 0, stream>>>(x, tmp, nw, xn);
  convw<<<576, 256, 0, stream>>>(wq, wk, wv, wo, bwqkv, bwo);
  gemm_f16<0><<<64 * 18, 256, 0, stream>>>(xn, bwqkv, bq, bk, bv,
                                           qbuf, kbuf, vtb, nullptr, 18);
  attn_fused5<<<768, 256, 0, stream>>>(qbuf, kbuf, vtb, aout);
  gemm_f16<1><<<64 * 6, 256, 0, stream>>>(aout, bwo, bo, nullptr, nullptr, nullptr,
                                          nullptr, nullptr, out, 6);
}